// Round 1
// baseline (809.878 us; speedup 1.0000x reference)
//
#include <hip/hip_runtime.h>
#include <cstdint>

// MoE: B=16384 rows, D=2048 feat, E=16 experts, C=64 classes/expert.
// All math fp32 (argmax outputs can't tolerate bf16 error vs np reference).
// Pipeline: coarse GEMM (splitK, deterministic partials) -> argmax+compaction
//           -> routed expert GEMM over compacted rows -> softmax/argmax.
static constexpr int B_ = 16384;
static constexpr int D_ = 2048;
static constexpr int E_ = 16;
static constexpr int C_ = 64;
static constexpr int KC = 32;       // K-chunk staged in LDS
static constexpr int TROWS = 256;   // rows per block tile
static constexpr int SPLITK = 4;    // K split for occupancy (deterministic reduce later)

// Generic fp32 tile GEMM: part[kz][row][c] = sum_{d in kz range} feat[grow][d]*W[c][d]
// W layout [NC][D_]. Rows via optional indirection list (per-expert compaction).
// LDS feature tile stored transposed [dd][row] with 8-col XOR swizzle so both
// the transposing scalar writes and the float4 outer-product reads are <=2-way
// bank conflicted (free per m136).
template <int RPT, int CPT, int NC>
__global__ __launch_bounds__(256) void gemm_tile(
    const float* __restrict__ feat, const float* __restrict__ Wall,
    const int* __restrict__ rowList, const int* __restrict__ cnt,
    float* __restrict__ part0,      // kz==0 slice (aliased onto d_out region)
    float* __restrict__ partRest)   // kz>=1 slices in ws
{
  __shared__ float fT[KC * TROWS];   // 32 KB
  __shared__ float wT[KC * NC];      // 8 KB (NC=64) / 2 KB (NC=16)
  __shared__ int rIdx[TROWS];

  const int tid = threadIdx.x;
  const int tile = blockIdx.x;
  const int e = blockIdx.y;
  const int kz = blockIdx.z;
  const int count = cnt ? cnt[e] : B_;
  if (tile * TROWS >= count) return;  // early-exit empty tiles (uniform)

  {
    const int slot = tile * TROWS + tid;
    int r = 0;
    if (slot < count) r = rowList ? rowList[e * B_ + slot] : slot;
    rIdx[tid] = r;
  }
  __syncthreads();

  // staging row indices are loop-invariant -> registers
  unsigned grows[8];
#pragma unroll
  for (int i = 0; i < 8; ++i) grows[i] = (unsigned)rIdx[(i * 256 + tid) >> 3];

  constexpr int CG = NC / CPT;  // threads along class dim
  const int cg = tid % CG;
  const int rg = tid / CG;

  float acc[RPT][CPT];
#pragma unroll
  for (int r = 0; r < RPT; ++r)
#pragma unroll
    for (int c = 0; c < CPT; ++c) acc[r][c] = 0.f;

  const float* We = Wall + (size_t)e * NC * D_;
  constexpr int KRANGE = D_ / SPLITK;  // 512
  const int k0 = kz * KRANGE;

  for (int ch = 0; ch < KRANGE / KC; ++ch) {
    const int kb = k0 + ch * KC;
    // ---- stage features: 256 rows x 32 d, transposed into fT[dd][row'] ----
#pragma unroll
    for (int i = 0; i < 8; ++i) {
      const int idx = i * 256 + tid;
      const int rl = idx >> 3, dc = idx & 7;
      const float4 v =
          *(const float4*)(feat + (size_t)grows[i] * D_ + kb + dc * 4);
      // swizzle: row-block (rl>>3) XORed with (dd>>2)==dc (same for 4 dds)
      const int sb = (((rl >> 3) ^ dc) << 3) + (rl & 7);
      float* p = &fT[(dc * 4) * TROWS + sb];
      p[0 * TROWS] = v.x;
      p[1 * TROWS] = v.y;
      p[2 * TROWS] = v.z;
      p[3 * TROWS] = v.w;
    }
    // ---- stage weights: NC x 32, transposed into wT[dd][c'] ----
    constexpr int WSLOTS = NC * (KC / 4);
#pragma unroll
    for (int w0 = 0; w0 < WSLOTS; w0 += 256) {
      const int idx = w0 + tid;
      if (idx < WSLOTS) {
        const int c = idx >> 3, dc = idx & 7;
        const float4 v =
            *(const float4*)(We + (size_t)c * D_ + kb + dc * 4);
        const int sb = (((c >> 3) ^ (dc & (NC / 8 - 1))) << 3) + (c & 7);
        float* p = &wT[(dc * 4) * NC + sb];
        p[0 * NC] = v.x;
        p[1 * NC] = v.y;
        p[2 * NC] = v.z;
        p[3 * NC] = v.w;
      }
    }
    __syncthreads();
    // ---- outer-product register tile ----
#pragma unroll
    for (int dd = 0; dd < KC; ++dd) {
      const int s = (dd >> 2) & 7;
      const int sw = (dd >> 2) & (NC / 8 - 1);
      float a[RPT], bb[CPT];
#pragma unroll
      for (int r4 = 0; r4 < RPT / 4; ++r4) {
        const int col = rg * RPT + r4 * 4;
        const float4 v =
            *(const float4*)&fT[dd * TROWS + (((col >> 3) ^ s) << 3) + (col & 7)];
        a[r4 * 4 + 0] = v.x;
        a[r4 * 4 + 1] = v.y;
        a[r4 * 4 + 2] = v.z;
        a[r4 * 4 + 3] = v.w;
      }
#pragma unroll
      for (int c4 = 0; c4 < CPT / 4; ++c4) {
        const int col = cg * CPT + c4 * 4;
        const float4 v =
            *(const float4*)&wT[dd * NC + (((col >> 3) ^ sw) << 3) + (col & 7)];
        bb[c4 * 4 + 0] = v.x;
        bb[c4 * 4 + 1] = v.y;
        bb[c4 * 4 + 2] = v.z;
        bb[c4 * 4 + 3] = v.w;
      }
#pragma unroll
      for (int r = 0; r < RPT; ++r)
#pragma unroll
        for (int c = 0; c < CPT; ++c) acc[r][c] += a[r] * bb[c];
    }
    __syncthreads();
  }

  // ---- epilogue: plain float4 stores to this kz's partial slice ----
  float* pk = kz ? (partRest + (size_t)(kz - 1) * B_ * NC) : part0;
#pragma unroll
  for (int r = 0; r < RPT; ++r) {
    const int lrow = rg * RPT + r;
    const int slot = tile * TROWS + lrow;
    if (slot < count) {
      const int grow = rIdx[lrow];
      float* dst = pk + (size_t)grow * NC + cg * CPT;
#pragma unroll
      for (int c4 = 0; c4 < CPT / 4; ++c4) {
        *(float4*)(dst + c4 * 4) =
            make_float4(acc[r][c4 * 4 + 0], acc[r][c4 * 4 + 1],
                        acc[r][c4 * 4 + 2], acc[r][c4 * 4 + 3]);
      }
    }
  }
}

// Reduce coarse partials (fixed order => deterministic), add bias, argmax,
// write coarse_output + expert_id, and build per-expert compacted row lists
// with block-aggregated atomics (16 global atomics per block, not 256).
__global__ __launch_bounds__(256) void coarse_finish(
    const float* __restrict__ cpart0, const float* __restrict__ cpartRest,
    const float* __restrict__ cb, float* __restrict__ out0,
    float* __restrict__ out1, int* __restrict__ eidArr, int* __restrict__ cnt,
    int* __restrict__ rowList) {
  __shared__ int lcnt[E_];
  __shared__ int lbase[E_];
  const int tid = threadIdx.x;
  if (tid < E_) lcnt[tid] = 0;
  __syncthreads();
  const int row = blockIdx.x * 256 + tid;

  float v[E_];
#pragma unroll
  for (int j = 0; j < E_; ++j) v[j] = cb[j];
#pragma unroll
  for (int kz = 0; kz < SPLITK; ++kz) {
    const float* p = (kz == 0) ? (cpart0 + (size_t)row * E_)
                               : (cpartRest + ((size_t)(kz - 1) * B_ + row) * E_);
#pragma unroll
    for (int j4 = 0; j4 < E_ / 4; ++j4) {
      const float4 t = *(const float4*)(p + j4 * 4);
      v[j4 * 4 + 0] += t.x;
      v[j4 * 4 + 1] += t.y;
      v[j4 * 4 + 2] += t.z;
      v[j4 * 4 + 3] += t.w;
    }
  }
  // first-occurrence argmax (strict >)
  int best = 0;
  float bv = v[0];
#pragma unroll
  for (int j = 1; j < E_; ++j)
    if (v[j] > bv) { bv = v[j]; best = j; }

  float* o0 = out0 + (size_t)row * E_;
#pragma unroll
  for (int j4 = 0; j4 < E_ / 4; ++j4)
    *(float4*)(o0 + j4 * 4) = make_float4(v[j4 * 4 + 0], v[j4 * 4 + 1],
                                          v[j4 * 4 + 2], v[j4 * 4 + 3]);
  out1[row] = (float)best;
  eidArr[row] = best;

  const int lpos = atomicAdd(&lcnt[best], 1);
  __syncthreads();
  if (tid < E_) lbase[tid] = atomicAdd(&cnt[tid], lcnt[tid]);
  __syncthreads();
  rowList[best * B_ + lbase[best] + lpos] = row;
}

// Wave-per-row (C=64 == wave size): reduce y partials (fixed order), add bias,
// softmax -> local_preds, first-occurrence argmax + expert class start.
__global__ __launch_bounds__(256) void finish_rows(
    const float* __restrict__ ypart0, const float* __restrict__ ypartRest,
    const float* __restrict__ eb, const int* __restrict__ eidArr,
    float* __restrict__ out2, float* __restrict__ out3) {
  const int lane = threadIdx.x & 63;
  const int row = (blockIdx.x * 256 + threadIdx.x) >> 6;
  const int eid = eidArr[row];

  float v = eb[eid * C_ + lane];
  v += ypart0[(size_t)row * C_ + lane];
#pragma unroll
  for (int kz = 1; kz < SPLITK; ++kz)
    v += ypartRest[((size_t)(kz - 1) * B_ + row) * C_ + lane];

  float m = v;
#pragma unroll
  for (int off = 32; off; off >>= 1) m = fmaxf(m, __shfl_xor(m, off, 64));
  const float p = __expf(v - m);
  float s = p;
#pragma unroll
  for (int off = 32; off; off >>= 1) s += __shfl_xor(s, off, 64);
  out2[(size_t)row * C_ + lane] = p / s;  // note: ypart0 aliases out2, read done

  float av = v;
  int ai = lane;
#pragma unroll
  for (int off = 32; off; off >>= 1) {
    const float ov = __shfl_xor(av, off, 64);
    const int oi = __shfl_xor(ai, off, 64);
    if (ov > av || (ov == av && oi < ai)) { av = ov; ai = oi; }
  }
  if (lane == 0) out3[row] = (float)(ai + (eid << 6));
}

extern "C" void kernel_launch(void* const* d_in, const int* in_sizes, int n_in,
                              void* d_out, int out_size, void* d_ws,
                              size_t ws_size, hipStream_t stream) {
  const float* feat = (const float*)d_in[0];  // [B, D]
  const float* cw = (const float*)d_in[1];    // [E, D]
  const float* cb = (const float*)d_in[2];    // [E]
  const float* ew = (const float*)d_in[3];    // [E, C, D]
  const float* eb = (const float*)d_in[4];    // [E, C]

  float* out0 = (float*)d_out;           // coarse_output [B, E]
  float* out1 = out0 + (size_t)B_ * E_;  // expert_id [B] (stored as float)
  float* out2 = out1 + B_;               // local_preds [B, C]
  float* out3 = out2 + (size_t)B_ * C_;  // global_preds [B]

  // ws layout: kz>=1 partial slices + routing metadata (~16.1 MB).
  // kz==0 slices alias the final output regions (same [row][col] mapping;
  // reducers read-then-overwrite the same element in the same thread).
  char* ws = (char*)d_ws;
  float* cpartRest = (float*)ws;                               // (SPLITK-1)*B*E
  float* ypartRest = cpartRest + (size_t)(SPLITK - 1) * B_ * E_;  // (SPLITK-1)*B*C
  int* rowList = (int*)(ypartRest + (size_t)(SPLITK - 1) * B_ * C_);  // E*B
  int* cnt = rowList + (size_t)E_ * B_;                        // E (pad 64)
  int* eidArr = cnt + 64;                                      // B

  hipMemsetAsync(cnt, 0, E_ * sizeof(int), stream);

  // 1) coarse partial GEMM: 64 row-tiles x 4 K-splits
  gemm_tile<4, 4, E_><<<dim3(B_ / TROWS, 1, SPLITK), 256, 0, stream>>>(
      feat, cw, nullptr, nullptr, out0, cpartRest);
  // 2) reduce + argmax + compaction
  coarse_finish<<<B_ / 256, 256, 0, stream>>>(out0, cpartRest, cb, out0, out1,
                                              eidArr, cnt, rowList);
  // 3) routed expert GEMM over compacted rows (grid covers worst-case counts)
  gemm_tile<8, 8, C_><<<dim3(B_ / TROWS, E_, SPLITK), 256, 0, stream>>>(
      feat, ew, rowList, cnt, out2, ypartRest);
  // 4) softmax + argmax + class-range start
  finish_rows<<<(B_ * 64) / 256, 256, 0, stream>>>(out2, ypartRest, eb, eidArr,
                                                   out2, out3);
}

// Round 2
// 410.122 us; speedup vs baseline: 1.9747x; 1.9747x over previous
//
#include <hip/hip_runtime.h>
#include <cstdint>

// MoE: B=16384 rows, D=2048 feat, E=16 experts, C=64 classes/expert.
// All math fp32 (argmax outputs can't tolerate bf16 error vs np reference).
// R2: flat device-built work schedule for the expert GEMM (round-1 early-exit
// grid piled 256 workers onto 16 CUs -> Occupancy 1.6%, 594us). Dense 1-D
// worker grids + register prefetch of next K-chunk.
static constexpr int B_ = 16384;
static constexpr int D_ = 2048;
static constexpr int E_ = 16;
static constexpr int C_ = 64;
static constexpr int KCH = 32;     // K-chunk staged in LDS
static constexpr int TR_E = 128;   // expert tile rows
static constexpr int SK_E = 4;     // expert split-K
static constexpr int TR_C = 256;   // coarse tile rows
static constexpr int SK_C = 8;     // coarse split-K
static constexpr int MAXITEMS = (B_ / TR_E) + E_ - 1 + 1;  // 144

// part[kz][row][c] = sum_{d in kz range} feat[grow][d]*W[c][d].  W: [NC][D_].
// Feature tile transposed in LDS [dd][row] with XOR swizzle (<=2-way conflicts,
// free per m136). FLAT mode: dense worker ids via device-built (e,tile) list.
template <int RPT, int CPT, int NC, int TR, int SK, bool FLAT>
__global__ __launch_bounds__(256, 4) void gemm_tile(
    const float* __restrict__ feat, const float* __restrict__ Wall,
    const int* __restrict__ rowList, const int* __restrict__ cnt,
    const int* __restrict__ sched, const int* __restrict__ nItems,
    float* __restrict__ part0,      // kz==0 slice (aliased onto d_out region)
    float* __restrict__ partRest)   // kz>=1 slices in ws
{
  constexpr int FITER = TR / 32;          // feature float4 loads/thread/chunk
  constexpr int WSLOTS = NC * 8;          // weight float4 slots/chunk
  constexpr int WITER = (WSLOTS + 255) / 256;
  constexpr int CG = NC / CPT;

  __shared__ float fT[KCH * TR];
  __shared__ float wT[KCH * NC];
  __shared__ int rIdx[TR];

  const int tid = threadIdx.x;
  int e, tile, kz;
  if (FLAT) {
    const int b = blockIdx.x;
    kz = b % SK;
    const int item = b / SK;
    if (item >= *nItems) return;  // dense tail exit only
    const int s = sched[item];
    e = s & 255;
    tile = s >> 8;
  } else {
    e = 0;
    tile = blockIdx.x;
    kz = blockIdx.z;
  }
  const int count = cnt ? cnt[e] : B_;

  if (tid < TR) {
    const int slot = tile * TR + tid;
    rIdx[tid] = (slot < count) ? (rowList ? rowList[e * B_ + slot] : slot) : 0;
  }
  __syncthreads();

  // loop-invariant staging constants -> registers
  unsigned grows[FITER];
  int dcf[FITER], sbf[FITER];
#pragma unroll
  for (int i = 0; i < FITER; ++i) {
    const int idx = i * 256 + tid;
    const int rl = idx >> 3;
    dcf[i] = idx & 7;
    grows[i] = (unsigned)rIdx[rl];
    sbf[i] = (((rl >> 3) ^ dcf[i]) << 3) + (rl & 7);
  }
  int wc[WITER], wdc[WITER], wsb[WITER];
  bool wact[WITER];
#pragma unroll
  for (int i = 0; i < WITER; ++i) {
    const int idx = i * 256 + tid;
    wact[i] = idx < WSLOTS;
    const int c = (idx < WSLOTS) ? (idx >> 3) : 0;
    wc[i] = c;
    wdc[i] = idx & 7;
    wsb[i] = (((c >> 3) ^ (wdc[i] & (NC / 8 - 1))) << 3) + (c & 7);
  }

  const int cg = tid % CG;
  const int rg = tid / CG;

  float acc[RPT][CPT];
#pragma unroll
  for (int r = 0; r < RPT; ++r)
#pragma unroll
    for (int c = 0; c < CPT; ++c) acc[r][c] = 0.f;

  const float* We = Wall + (size_t)e * NC * D_;
  constexpr int KRANGE = D_ / SK;
  constexpr int NCH = KRANGE / KCH;
  const int k0 = kz * KRANGE;

  // prefetch chunk 0 into registers
  float4 pf[FITER], pw[WITER];
#pragma unroll
  for (int i = 0; i < FITER; ++i)
    pf[i] = *(const float4*)(feat + (size_t)grows[i] * D_ + k0 + dcf[i] * 4);
#pragma unroll
  for (int i = 0; i < WITER; ++i)
    if (wact[i])
      pw[i] = *(const float4*)(We + (size_t)wc[i] * D_ + k0 + wdc[i] * 4);

  for (int ch = 0; ch < NCH; ++ch) {
    // drain prefetch regs -> LDS (transposed + swizzled)
#pragma unroll
    for (int i = 0; i < FITER; ++i) {
      float* p = &fT[(dcf[i] * 4) * TR + sbf[i]];
      p[0 * TR] = pf[i].x;
      p[1 * TR] = pf[i].y;
      p[2 * TR] = pf[i].z;
      p[3 * TR] = pf[i].w;
    }
#pragma unroll
    for (int i = 0; i < WITER; ++i)
      if (wact[i]) {
        float* p = &wT[(wdc[i] * 4) * NC + wsb[i]];
        p[0 * NC] = pw[i].x;
        p[1 * NC] = pw[i].y;
        p[2 * NC] = pw[i].z;
        p[3 * NC] = pw[i].w;
      }
    __syncthreads();
    // issue next chunk's global loads early; they overlap the dd-loop
    if (ch + 1 < NCH) {
      const int kb = k0 + (ch + 1) * KCH;
#pragma unroll
      for (int i = 0; i < FITER; ++i)
        pf[i] = *(const float4*)(feat + (size_t)grows[i] * D_ + kb + dcf[i] * 4);
#pragma unroll
      for (int i = 0; i < WITER; ++i)
        if (wact[i])
          pw[i] = *(const float4*)(We + (size_t)wc[i] * D_ + kb + wdc[i] * 4);
    }
    // outer-product register tile
#pragma unroll
    for (int dd = 0; dd < KCH; ++dd) {
      const int s = dd >> 2;
      const int sw = s & (NC / 8 - 1);
      float a[RPT], bb[CPT];
#pragma unroll
      for (int r4 = 0; r4 < RPT / 4; ++r4) {
        const int col = rg * RPT + r4 * 4;
        const float4 v =
            *(const float4*)&fT[dd * TR + (((col >> 3) ^ s) << 3) + (col & 7)];
        a[r4 * 4 + 0] = v.x;
        a[r4 * 4 + 1] = v.y;
        a[r4 * 4 + 2] = v.z;
        a[r4 * 4 + 3] = v.w;
      }
      if constexpr (CPT >= 4) {
#pragma unroll
        for (int c4 = 0; c4 < CPT / 4; ++c4) {
          const int col = cg * CPT + c4 * 4;
          const float4 v =
              *(const float4*)&wT[dd * NC + (((col >> 3) ^ sw) << 3) + (col & 7)];
          bb[c4 * 4 + 0] = v.x;
          bb[c4 * 4 + 1] = v.y;
          bb[c4 * 4 + 2] = v.z;
          bb[c4 * 4 + 3] = v.w;
        }
      } else {  // CPT == 2
        const int col = cg * 2;
        const float2 v =
            *(const float2*)&wT[dd * NC + (((col >> 3) ^ sw) << 3) + (col & 7)];
        bb[0] = v.x;
        bb[1] = v.y;
      }
#pragma unroll
      for (int r = 0; r < RPT; ++r)
#pragma unroll
        for (int c = 0; c < CPT; ++c) acc[r][c] += a[r] * bb[c];
    }
    __syncthreads();
  }

  // epilogue: plain vector stores to this kz's partial slice
  float* pk = kz ? (partRest + (size_t)(kz - 1) * B_ * NC) : part0;
#pragma unroll
  for (int r = 0; r < RPT; ++r) {
    const int lrow = rg * RPT + r;
    const int slot = tile * TR + lrow;
    if (slot < count) {
      const int grow = rIdx[lrow];
      float* dst = pk + (size_t)grow * NC + cg * CPT;
      if constexpr (CPT >= 4) {
#pragma unroll
        for (int c4 = 0; c4 < CPT / 4; ++c4)
          *(float4*)(dst + c4 * 4) =
              make_float4(acc[r][c4 * 4 + 0], acc[r][c4 * 4 + 1],
                          acc[r][c4 * 4 + 2], acc[r][c4 * 4 + 3]);
      } else {
        *(float2*)dst = make_float2(acc[r][0], acc[r][1]);
      }
    }
  }
}

// Reduce coarse partials (fixed order => deterministic), add bias, argmax,
// write coarse_output + expert_id, build compacted row lists (block-aggregated
// atomics: 16 global atomics per block).
__global__ __launch_bounds__(256) void coarse_finish(
    const float* __restrict__ cpart0, const float* __restrict__ cpartRest,
    const float* __restrict__ cb, float* __restrict__ out0,
    float* __restrict__ out1, int* __restrict__ eidArr, int* __restrict__ cnt,
    int* __restrict__ rowList) {
  __shared__ int lcnt[E_];
  __shared__ int lbase[E_];
  const int tid = threadIdx.x;
  if (tid < E_) lcnt[tid] = 0;
  __syncthreads();
  const int row = blockIdx.x * 256 + tid;

  float v[E_];
#pragma unroll
  for (int j = 0; j < E_; ++j) v[j] = cb[j];
#pragma unroll
  for (int kz = 0; kz < SK_C; ++kz) {
    const float* p = (kz == 0) ? (cpart0 + (size_t)row * E_)
                               : (cpartRest + ((size_t)(kz - 1) * B_ + row) * E_);
#pragma unroll
    for (int j4 = 0; j4 < E_ / 4; ++j4) {
      const float4 t = *(const float4*)(p + j4 * 4);
      v[j4 * 4 + 0] += t.x;
      v[j4 * 4 + 1] += t.y;
      v[j4 * 4 + 2] += t.z;
      v[j4 * 4 + 3] += t.w;
    }
  }
  int best = 0;
  float bv = v[0];
#pragma unroll
  for (int j = 1; j < E_; ++j)
    if (v[j] > bv) { bv = v[j]; best = j; }

  float* o0 = out0 + (size_t)row * E_;
#pragma unroll
  for (int j4 = 0; j4 < E_ / 4; ++j4)
    *(float4*)(o0 + j4 * 4) = make_float4(v[j4 * 4 + 0], v[j4 * 4 + 1],
                                          v[j4 * 4 + 2], v[j4 * 4 + 3]);
  out1[row] = (float)best;
  eidArr[row] = best;

  const int lpos = atomicAdd(&lcnt[best], 1);
  __syncthreads();
  if (tid < E_) lbase[tid] = atomicAdd(&cnt[tid], lcnt[tid]);
  __syncthreads();
  rowList[best * B_ + lbase[best] + lpos] = row;
}

// Build the dense (e, tile) worker list for the expert GEMM.
__global__ void make_schedule(const int* __restrict__ cnt,
                              int* __restrict__ sched,
                              int* __restrict__ nItems) {
  if (threadIdx.x == 0 && blockIdx.x == 0) {
    int it = 0;
    for (int e = 0; e < E_; ++e) {
      const int t = (cnt[e] + TR_E - 1) / TR_E;
      for (int k = 0; k < t; ++k) sched[it++] = e | (k << 8);
    }
    *nItems = it;
  }
}

// Wave-per-row (C=64 == wave): reduce y partials (fixed order), add bias,
// softmax -> local_preds, first-occurrence argmax + expert class start.
__global__ __launch_bounds__(256) void finish_rows(
    const float* __restrict__ ypart0, const float* __restrict__ ypartRest,
    const float* __restrict__ eb, const int* __restrict__ eidArr,
    float* __restrict__ out2, float* __restrict__ out3) {
  const int lane = threadIdx.x & 63;
  const int row = (blockIdx.x * 256 + threadIdx.x) >> 6;
  const int eid = eidArr[row];

  float v = eb[eid * C_ + lane];
  v += ypart0[(size_t)row * C_ + lane];
#pragma unroll
  for (int kz = 1; kz < SK_E; ++kz)
    v += ypartRest[((size_t)(kz - 1) * B_ + row) * C_ + lane];

  float m = v;
#pragma unroll
  for (int off = 32; off; off >>= 1) m = fmaxf(m, __shfl_xor(m, off, 64));
  const float p = __expf(v - m);
  float s = p;
#pragma unroll
  for (int off = 32; off; off >>= 1) s += __shfl_xor(s, off, 64);
  out2[(size_t)row * C_ + lane] = p / s;  // ypart0 aliases out2; read done

  float av = v;
  int ai = lane;
#pragma unroll
  for (int off = 32; off; off >>= 1) {
    const float ov = __shfl_xor(av, off, 64);
    const int oi = __shfl_xor(ai, off, 64);
    if (ov > av || (ov == av && oi < ai)) { av = ov; ai = oi; }
  }
  if (lane == 0) out3[row] = (float)(ai + (eid << 6));
}

extern "C" void kernel_launch(void* const* d_in, const int* in_sizes, int n_in,
                              void* d_out, int out_size, void* d_ws,
                              size_t ws_size, hipStream_t stream) {
  const float* feat = (const float*)d_in[0];  // [B, D]
  const float* cw = (const float*)d_in[1];    // [E, D]
  const float* cb = (const float*)d_in[2];    // [E]
  const float* ew = (const float*)d_in[3];    // [E, C, D]
  const float* eb = (const float*)d_in[4];    // [E, C]

  float* out0 = (float*)d_out;           // coarse_output [B, E]
  float* out1 = out0 + (size_t)B_ * E_;  // expert_id [B] (as float)
  float* out2 = out1 + B_;               // local_preds [B, C]
  float* out3 = out2 + (size_t)B_ * C_;  // global_preds [B]

  // ws (~21.2 MB): kz>=1 partial slices + routing metadata. kz==0 slices
  // alias the output regions (same element, same reducing thread).
  char* ws = (char*)d_ws;
  float* cpartRest = (float*)ws;                                  // 7*B*E
  float* ypartRest = cpartRest + (size_t)(SK_C - 1) * B_ * E_;    // 3*B*C
  int* rowList = (int*)(ypartRest + (size_t)(SK_E - 1) * B_ * C_);  // E*B
  int* cnt = rowList + (size_t)E_ * B_;   // E (pad 64)
  int* eidArr = cnt + 64;                 // B
  int* sched = eidArr + B_;               // MAXITEMS (pad 256)
  int* nItems = sched + 256;              // 1

  hipMemsetAsync(cnt, 0, E_ * sizeof(int), stream);

  // 1) coarse GEMM: dense grid (64,1,8) -> ids 0..511, ~2 blocks/CU
  gemm_tile<8, 2, E_, TR_C, SK_C, false>
      <<<dim3(B_ / TR_C, 1, SK_C), 256, 0, stream>>>(
          feat, cw, nullptr, nullptr, nullptr, nullptr, out0, cpartRest);
  // 2) reduce + argmax + compaction
  coarse_finish<<<B_ / 256, 256, 0, stream>>>(out0, cpartRest, cb, out0, out1,
                                              eidArr, cnt, rowList);
  // 3) flat schedule, then expert GEMM over a dense 1-D worker grid
  make_schedule<<<1, 64, 0, stream>>>(cnt, sched, nItems);
  gemm_tile<8, 4, C_, TR_E, SK_E, true>
      <<<MAXITEMS * SK_E, 256, 0, stream>>>(feat, ew, rowList, cnt, sched,
                                            nItems, out2, ypartRest);
  // 4) softmax + argmax + class-range start
  finish_rows<<<(B_ * 64) / 256, 256, 0, stream>>>(out2, ypartRest, eb, eidArr,
                                                   out2, out3);
}

// Round 3
// 298.939 us; speedup vs baseline: 2.7092x; 1.3719x over previous
//
#include <hip/hip_runtime.h>
#include <cstdint>

// MoE: B=16384 rows, D=2048 feat, E=16 experts, C=64 classes/expert.
// All math fp32 (argmax outputs can't tolerate bf16 error vs np reference).
// R3: kill register spills (R2: VGPR=64 cap + ~100 VGPR demand -> 100 MB of
// scratch WRITE_SIZE), denser grids (expert TR 128->64, ~1040 blocks; coarse
// TR 256->128, SK 8 -> 1024 blocks), no launch_bounds min-waves arg.
static constexpr int B_ = 16384;
static constexpr int D_ = 2048;
static constexpr int E_ = 16;
static constexpr int C_ = 64;
static constexpr int KCH = 32;     // K-chunk staged in LDS
static constexpr int TR_E = 64;    // expert tile rows
static constexpr int SK_E = 4;     // expert split-K
static constexpr int TR_C = 128;   // coarse tile rows
static constexpr int SK_C = 8;     // coarse split-K
static constexpr int MAXITEMS = (B_ / TR_E) + E_;  // 272 worst case

// part[kz][row][c] = sum_{d in kz range} feat[grow][d]*W[c][d].  W: [NC][D_].
// Feature tile transposed in LDS [dd][row] with XOR swizzle (<=2-way bank
// aliasing, free per m136). FLAT mode: dense worker ids from device-built
// (e,tile) list so active blocks spread over all CUs.
template <int RPT, int CPT, int NC, int TR, int SK, bool FLAT>
__global__ __launch_bounds__(256) void gemm_tile(
    const float* __restrict__ feat, const float* __restrict__ Wall,
    const int* __restrict__ rowList, const int* __restrict__ cnt,
    const int* __restrict__ sched, const int* __restrict__ nItems,
    float* __restrict__ part0,      // kz==0 slice (aliased onto d_out region)
    float* __restrict__ partRest)   // kz>=1 slices in ws
{
  constexpr int FITER = TR / 32;          // feature float4 loads/thread/chunk
  constexpr int WSLOTS = NC * 8;          // weight float4 slots/chunk
  constexpr int WITER = (WSLOTS + 255) / 256;
  constexpr int CG = NC / CPT;

  __shared__ float fT[KCH * TR];
  __shared__ float wT[KCH * NC];
  __shared__ int rIdx[TR];

  const int tid = threadIdx.x;
  int e, tile, kz;
  if (FLAT) {
    const int b = blockIdx.x;
    kz = b % SK;
    const int item = b / SK;
    if (item >= *nItems) return;  // dense tail exit only
    const int s = sched[item];
    e = s & 255;
    tile = s >> 8;
  } else {
    e = 0;
    tile = blockIdx.x;
    kz = blockIdx.z;
  }
  const int count = cnt ? cnt[e] : B_;

  if (tid < TR) {
    const int slot = tile * TR + tid;
    rIdx[tid] = (slot < count) ? (rowList ? rowList[e * B_ + slot] : slot) : 0;
  }
  __syncthreads();

  // loop-invariant staging constants -> registers
  unsigned grows[FITER];
  int dcf[FITER], sbf[FITER];
#pragma unroll
  for (int i = 0; i < FITER; ++i) {
    const int idx = i * 256 + tid;
    const int rl = idx >> 3;
    dcf[i] = idx & 7;
    grows[i] = (unsigned)rIdx[rl];
    sbf[i] = (((rl >> 3) ^ dcf[i]) << 3) + (rl & 7);
  }
  int wc[WITER], wdc[WITER], wsb[WITER];
  bool wact[WITER];
#pragma unroll
  for (int i = 0; i < WITER; ++i) {
    const int idx = i * 256 + tid;
    wact[i] = idx < WSLOTS;
    const int c = (idx < WSLOTS) ? (idx >> 3) : 0;
    wc[i] = c;
    wdc[i] = idx & 7;
    wsb[i] = (((c >> 3) ^ (wdc[i] & (NC / 8 - 1))) << 3) + (c & 7);
  }

  const int cg = tid % CG;
  const int rg = tid / CG;

  float acc[RPT][CPT];
#pragma unroll
  for (int r = 0; r < RPT; ++r)
#pragma unroll
    for (int c = 0; c < CPT; ++c) acc[r][c] = 0.f;

  const float* We = Wall + (size_t)e * NC * D_;
  constexpr int KRANGE = D_ / SK;
  constexpr int NCH = KRANGE / KCH;
  const int k0 = kz * KRANGE;

  // prefetch chunk 0 into registers
  float4 pf[FITER], pw[WITER];
#pragma unroll
  for (int i = 0; i < FITER; ++i)
    pf[i] = *(const float4*)(feat + (size_t)grows[i] * D_ + k0 + dcf[i] * 4);
#pragma unroll
  for (int i = 0; i < WITER; ++i)
    if (wact[i])
      pw[i] = *(const float4*)(We + (size_t)wc[i] * D_ + k0 + wdc[i] * 4);

  for (int ch = 0; ch < NCH; ++ch) {
    // drain prefetch regs -> LDS (transposed + swizzled)
#pragma unroll
    for (int i = 0; i < FITER; ++i) {
      float* p = &fT[(dcf[i] * 4) * TR + sbf[i]];
      p[0 * TR] = pf[i].x;
      p[1 * TR] = pf[i].y;
      p[2 * TR] = pf[i].z;
      p[3 * TR] = pf[i].w;
    }
#pragma unroll
    for (int i = 0; i < WITER; ++i)
      if (wact[i]) {
        float* p = &wT[(wdc[i] * 4) * NC + wsb[i]];
        p[0 * NC] = pw[i].x;
        p[1 * NC] = pw[i].y;
        p[2 * NC] = pw[i].z;
        p[3 * NC] = pw[i].w;
      }
    __syncthreads();
    // issue next chunk's global loads early; they overlap the dd-loop
    if (ch + 1 < NCH) {
      const int kb = k0 + (ch + 1) * KCH;
#pragma unroll
      for (int i = 0; i < FITER; ++i)
        pf[i] = *(const float4*)(feat + (size_t)grows[i] * D_ + kb + dcf[i] * 4);
#pragma unroll
      for (int i = 0; i < WITER; ++i)
        if (wact[i])
          pw[i] = *(const float4*)(We + (size_t)wc[i] * D_ + kb + wdc[i] * 4);
    }
    // outer-product register tile
#pragma unroll
    for (int dd = 0; dd < KCH; ++dd) {
      const int s = dd >> 2;
      const int sw = s & (NC / 8 - 1);
      float a[RPT], bb[CPT];
#pragma unroll
      for (int r4 = 0; r4 < RPT / 4; ++r4) {
        const int col = rg * RPT + r4 * 4;
        const float4 v =
            *(const float4*)&fT[dd * TR + (((col >> 3) ^ s) << 3) + (col & 7)];
        a[r4 * 4 + 0] = v.x;
        a[r4 * 4 + 1] = v.y;
        a[r4 * 4 + 2] = v.z;
        a[r4 * 4 + 3] = v.w;
      }
      if constexpr (CPT >= 4) {
#pragma unroll
        for (int c4 = 0; c4 < CPT / 4; ++c4) {
          const int col = cg * CPT + c4 * 4;
          const float4 v =
              *(const float4*)&wT[dd * NC + (((col >> 3) ^ sw) << 3) + (col & 7)];
          bb[c4 * 4 + 0] = v.x;
          bb[c4 * 4 + 1] = v.y;
          bb[c4 * 4 + 2] = v.z;
          bb[c4 * 4 + 3] = v.w;
        }
      } else {  // CPT == 2
        const int col = cg * 2;
        const float2 v =
            *(const float2*)&wT[dd * NC + (((col >> 3) ^ sw) << 3) + (col & 7)];
        bb[0] = v.x;
        bb[1] = v.y;
      }
#pragma unroll
      for (int r = 0; r < RPT; ++r)
#pragma unroll
        for (int c = 0; c < CPT; ++c) acc[r][c] += a[r] * bb[c];
    }
    __syncthreads();
  }

  // epilogue: plain vector stores to this kz's partial slice
  float* pk = kz ? (partRest + (size_t)(kz - 1) * B_ * NC) : part0;
#pragma unroll
  for (int r = 0; r < RPT; ++r) {
    const int lrow = rg * RPT + r;
    const int slot = tile * TR + lrow;
    if (slot < count) {
      const int grow = rIdx[lrow];
      float* dst = pk + (size_t)grow * NC + cg * CPT;
      if constexpr (CPT >= 4) {
#pragma unroll
        for (int c4 = 0; c4 < CPT / 4; ++c4)
          *(float4*)(dst + c4 * 4) =
              make_float4(acc[r][c4 * 4 + 0], acc[r][c4 * 4 + 1],
                          acc[r][c4 * 4 + 2], acc[r][c4 * 4 + 3]);
      } else {
        *(float2*)dst = make_float2(acc[r][0], acc[r][1]);
      }
    }
  }
}

// Reduce coarse partials (fixed order => deterministic), add bias, argmax,
// write coarse_output + expert_id, build compacted row lists (block-aggregated
// atomics: 16 global atomics per block).
__global__ __launch_bounds__(256) void coarse_finish(
    const float* __restrict__ cpart0, const float* __restrict__ cpartRest,
    const float* __restrict__ cb, float* __restrict__ out0,
    float* __restrict__ out1, int* __restrict__ eidArr, int* __restrict__ cnt,
    int* __restrict__ rowList) {
  __shared__ int lcnt[E_];
  __shared__ int lbase[E_];
  const int tid = threadIdx.x;
  if (tid < E_) lcnt[tid] = 0;
  __syncthreads();
  const int row = blockIdx.x * 256 + tid;

  float v[E_];
#pragma unroll
  for (int j = 0; j < E_; ++j) v[j] = cb[j];
#pragma unroll
  for (int kz = 0; kz < SK_C; ++kz) {
    const float* p = (kz == 0) ? (cpart0 + (size_t)row * E_)
                               : (cpartRest + ((size_t)(kz - 1) * B_ + row) * E_);
#pragma unroll
    for (int j4 = 0; j4 < E_ / 4; ++j4) {
      const float4 t = *(const float4*)(p + j4 * 4);
      v[j4 * 4 + 0] += t.x;
      v[j4 * 4 + 1] += t.y;
      v[j4 * 4 + 2] += t.z;
      v[j4 * 4 + 3] += t.w;
    }
  }
  int best = 0;
  float bv = v[0];
#pragma unroll
  for (int j = 1; j < E_; ++j)
    if (v[j] > bv) { bv = v[j]; best = j; }

  float* o0 = out0 + (size_t)row * E_;
#pragma unroll
  for (int j4 = 0; j4 < E_ / 4; ++j4)
    *(float4*)(o0 + j4 * 4) = make_float4(v[j4 * 4 + 0], v[j4 * 4 + 1],
                                          v[j4 * 4 + 2], v[j4 * 4 + 3]);
  out1[row] = (float)best;
  eidArr[row] = best;

  const int lpos = atomicAdd(&lcnt[best], 1);
  __syncthreads();
  if (tid < E_) lbase[tid] = atomicAdd(&cnt[tid], lcnt[tid]);
  __syncthreads();
  rowList[best * B_ + lbase[best] + lpos] = row;
}

// Build the dense (e, tile) worker list for the expert GEMM (parallel).
__global__ void make_schedule(const int* __restrict__ cnt,
                              int* __restrict__ sched,
                              int* __restrict__ nItems) {
  __shared__ int tiles[E_];
  __shared__ int offs[E_];
  const int t = threadIdx.x;
  if (t < E_) tiles[t] = (cnt[t] + TR_E - 1) / TR_E;
  __syncthreads();
  if (t == 0) {
    int acc = 0;
    for (int e = 0; e < E_; ++e) {
      offs[e] = acc;
      acc += tiles[e];
    }
    *nItems = acc;
  }
  __syncthreads();
  if (t < E_) {
    const int o = offs[t], n = tiles[t];
    for (int k = 0; k < n; ++k) sched[o + k] = t | (k << 8);
  }
}

// Wave-per-row (C=64 == wave): reduce y partials (fixed order), add bias,
// softmax -> local_preds, first-occurrence argmax + expert class start.
__global__ __launch_bounds__(256) void finish_rows(
    const float* __restrict__ ypart0, const float* __restrict__ ypartRest,
    const float* __restrict__ eb, const int* __restrict__ eidArr,
    float* __restrict__ out2, float* __restrict__ out3) {
  const int lane = threadIdx.x & 63;
  const int row = (blockIdx.x * 256 + threadIdx.x) >> 6;
  const int eid = eidArr[row];

  float v = eb[eid * C_ + lane];
  v += ypart0[(size_t)row * C_ + lane];
#pragma unroll
  for (int kz = 1; kz < SK_E; ++kz)
    v += ypartRest[((size_t)(kz - 1) * B_ + row) * C_ + lane];

  float m = v;
#pragma unroll
  for (int off = 32; off; off >>= 1) m = fmaxf(m, __shfl_xor(m, off, 64));
  const float p = __expf(v - m);
  float s = p;
#pragma unroll
  for (int off = 32; off; off >>= 1) s += __shfl_xor(s, off, 64);
  out2[(size_t)row * C_ + lane] = p / s;  // ypart0 aliases out2; read done

  float av = v;
  int ai = lane;
#pragma unroll
  for (int off = 32; off; off >>= 1) {
    const float ov = __shfl_xor(av, off, 64);
    const int oi = __shfl_xor(ai, off, 64);
    if (ov > av || (ov == av && oi < ai)) { av = ov; ai = oi; }
  }
  if (lane == 0) out3[row] = (float)(ai + (eid << 6));
}

extern "C" void kernel_launch(void* const* d_in, const int* in_sizes, int n_in,
                              void* d_out, int out_size, void* d_ws,
                              size_t ws_size, hipStream_t stream) {
  const float* feat = (const float*)d_in[0];  // [B, D]
  const float* cw = (const float*)d_in[1];    // [E, D]
  const float* cb = (const float*)d_in[2];    // [E]
  const float* ew = (const float*)d_in[3];    // [E, C, D]
  const float* eb = (const float*)d_in[4];    // [E, C]

  float* out0 = (float*)d_out;           // coarse_output [B, E]
  float* out1 = out0 + (size_t)B_ * E_;  // expert_id [B] (as float)
  float* out2 = out1 + B_;               // local_preds [B, C]
  float* out3 = out2 + (size_t)B_ * C_;  // global_preds [B]

  // ws (~21.0 MB): kz>=1 partial slices + routing metadata. kz==0 slices
  // alias the output regions (same element, same reducing thread).
  char* ws = (char*)d_ws;
  float* cpartRest = (float*)ws;                                  // 7*B*E
  float* ypartRest = cpartRest + (size_t)(SK_C - 1) * B_ * E_;    // 3*B*C
  int* rowList = (int*)(ypartRest + (size_t)(SK_E - 1) * B_ * C_);  // E*B
  int* cnt = rowList + (size_t)E_ * B_;   // E (pad 64)
  int* eidArr = cnt + 64;                 // B
  int* sched = eidArr + B_;               // MAXITEMS (pad 512)
  int* nItems = sched + 512;              // 1

  hipMemsetAsync(cnt, 0, E_ * sizeof(int), stream);

  // 1) coarse GEMM: dense grid (128,1,8) = 1024 blocks (~4/CU)
  gemm_tile<4, 2, E_, TR_C, SK_C, false>
      <<<dim3(B_ / TR_C, 1, SK_C), 256, 0, stream>>>(
          feat, cw, nullptr, nullptr, nullptr, nullptr, out0, cpartRest);
  // 2) reduce + argmax + compaction
  coarse_finish<<<B_ / 256, 256, 0, stream>>>(out0, cpartRest, cb, out0, out1,
                                              eidArr, cnt, rowList);
  // 3) flat schedule, then expert GEMM over a dense 1-D worker grid
  make_schedule<<<1, 64, 0, stream>>>(cnt, sched, nItems);
  gemm_tile<4, 4, C_, TR_E, SK_E, true>
      <<<MAXITEMS * SK_E, 256, 0, stream>>>(feat, ew, rowList, cnt, sched,
                                            nItems, out2, ypartRest);
  // 4) softmax + argmax + class-range start
  finish_rows<<<(B_ * 64) / 256, 256, 0, stream>>>(out2, ypartRest, eb, eidArr,
                                                   out2, out3);
}